// Round 1
// baseline (327.790 us; speedup 1.0000x reference)
//
#include <hip/hip_runtime.h>

#define TILE 32
#define IN_TILE 38            // TILE + WIN - 1
#define LSTRIDE 39            // padded LDS stride (odd -> conflict-light column reads)
#define IMG 512
#define VALID 506             // IMG - 6
#define NPLANES 96            // 32 * 3

__global__ __launch_bounds__(256) void ssim_tile_kernel(
    const float* __restrict__ pred,
    const float* __restrict__ target,
    double* __restrict__ accum)
{
    __shared__ float sx[IN_TILE * LSTRIDE];
    __shared__ float sy[IN_TILE * LSTRIDE];
    __shared__ float vx [TILE * LSTRIDE];
    __shared__ float vy [TILE * LSTRIDE];
    __shared__ float vxx[TILE * LSTRIDE];
    __shared__ float vyy[TILE * LSTRIDE];
    __shared__ float vxy[TILE * LSTRIDE];
    __shared__ float warp_sums[4];

    const int plane = blockIdx.z;
    const int i0 = blockIdx.y * TILE;     // output-tile top row (= input top row)
    const int j0 = blockIdx.x * TILE;     // output-tile left col
    const int tid = threadIdx.x;
    const size_t base = (size_t)plane * IMG * IMG;

    // ---- phase 1: stage input halo tile (38x38) for both images ----
    for (int idx = tid; idx < IN_TILE * IN_TILE; idx += 256) {
        int r = idx / IN_TILE;
        int c = idx - r * IN_TILE;
        int ir = min(i0 + r, IMG - 1);    // clamped loads only feed invalid outputs
        int ic = min(j0 + c, IMG - 1);
        size_t g = base + (size_t)ir * IMG + ic;
        sx[r * LSTRIDE + c] = pred[g];
        sy[r * LSTRIDE + c] = target[g];
    }
    __syncthreads();

    // ---- phase 2: vertical 7-tap sums of the 5 moments ----
    for (int p = tid; p < TILE * IN_TILE; p += 256) {
        int row = p / IN_TILE;            // output row within tile 0..31
        int col = p - row * IN_TILE;      // column 0..37
        float ax = 0.f, ay = 0.f, axx = 0.f, ayy = 0.f, axy = 0.f;
        #pragma unroll
        for (int k = 0; k < 7; k++) {
            float px = sx[(row + k) * LSTRIDE + col];
            float py = sy[(row + k) * LSTRIDE + col];
            ax  += px;       ay  += py;
            axx += px * px;  ayy += py * py;  axy += px * py;
        }
        vx [row * LSTRIDE + col] = ax;
        vy [row * LSTRIDE + col] = ay;
        vxx[row * LSTRIDE + col] = axx;
        vyy[row * LSTRIDE + col] = ayy;
        vxy[row * LSTRIDE + col] = axy;
    }
    __syncthreads();

    // ---- phase 3: horizontal 7-tap sums, SSIM, partial reduce ----
    const int row = tid >> 3;             // 0..31
    const int c0  = (tid & 7) * 4;        // 0,4,...,28
    const int rs  = row * LSTRIDE;

    float ax = 0.f, ay = 0.f, axx = 0.f, ayy = 0.f, axy = 0.f;
    #pragma unroll
    for (int k = 0; k < 7; k++) {
        ax  += vx [rs + c0 + k];
        ay  += vy [rs + c0 + k];
        axx += vxx[rs + c0 + k];
        ayy += vyy[rs + c0 + k];
        axy += vxy[rs + c0 + k];
    }

    const float inv_n    = 1.0f / 49.0f;
    const float cov_norm = 49.0f / 48.0f;
    const float C1 = 4.0e-4f;             // (0.01*2)^2
    const float C2 = 3.6e-3f;             // (0.03*2)^2

    float local = 0.0f;
    const int oy = i0 + row;
    #pragma unroll
    for (int j = 0; j < 4; j++) {
        const int ox = j0 + c0 + j;
        if (oy < VALID && ox < VALID) {
            float ux  = ax  * inv_n;
            float uy  = ay  * inv_n;
            float uxx = axx * inv_n;
            float uyy = ayy * inv_n;
            float uxy = axy * inv_n;
            float vvx  = cov_norm * (uxx - ux * ux);
            float vvy  = cov_norm * (uyy - uy * uy);
            float vvxy = cov_norm * (uxy - ux * uy);
            float S = ((2.0f * ux * uy + C1) * (2.0f * vvxy + C2)) /
                      ((ux * ux + uy * uy + C1) * (vvx + vvy + C2));
            local += S;
        }
        if (j < 3) {
            int ca = c0 + 7 + j, cs = c0 + j;
            ax  += vx [rs + ca] - vx [rs + cs];
            ay  += vy [rs + ca] - vy [rs + cs];
            axx += vxx[rs + ca] - vxx[rs + cs];
            ayy += vyy[rs + ca] - vyy[rs + cs];
            axy += vxy[rs + ca] - vxy[rs + cs];
        }
    }

    // wave-64 butterfly reduce, then cross-wave via LDS, one atomic per block
    #pragma unroll
    for (int off = 32; off > 0; off >>= 1)
        local += __shfl_down(local, off, 64);
    if ((tid & 63) == 0) warp_sums[tid >> 6] = local;
    __syncthreads();
    if (tid == 0) {
        float s = warp_sums[0] + warp_sums[1] + warp_sums[2] + warp_sums[3];
        atomicAdd(accum, (double)s);
    }
}

__global__ void ssim_finalize_kernel(const double* __restrict__ accum,
                                     float* __restrict__ out)
{
    const double n_valid = (double)NPLANES * (double)VALID * (double)VALID;
    out[0] = (float)(1.0 - accum[0] / n_valid);
}

extern "C" void kernel_launch(void* const* d_in, const int* in_sizes, int n_in,
                              void* d_out, int out_size, void* d_ws, size_t ws_size,
                              hipStream_t stream) {
    const float* pred   = (const float*)d_in[0];
    const float* target = (const float*)d_in[1];
    float* out = (float*)d_out;
    double* accum = (double*)d_ws;

    hipMemsetAsync(d_ws, 0, sizeof(double), stream);

    dim3 grid((VALID + TILE - 1) / TILE,   // 16
              (VALID + TILE - 1) / TILE,   // 16
              NPLANES);                    // 96
    ssim_tile_kernel<<<grid, 256, 0, stream>>>(pred, target, accum);
    ssim_finalize_kernel<<<1, 1, 0, stream>>>(accum, out);
}

// Round 2
// 88.289 us; speedup vs baseline: 3.7127x; 3.7127x over previous
//
#include <hip/hip_runtime.h>

#define IMG 512
#define VALID 506           // IMG - 6
#define NPLANES 96          // 32 * 3
#define BAND_ROWS 64        // output rows per band (last band: 58)
#define NBANDS 8
#define HSTRIDE 520         // padded LDS row stride (floats)

__device__ __forceinline__ float ssim_val(const float s[5]) {
    const float inv_n = 1.0f / 49.0f;
    const float cn    = 49.0f / 48.0f;
    const float C1 = 4.0e-4f;           // (0.01*2)^2
    const float C2 = 3.6e-3f;           // (0.03*2)^2
    float ux  = s[0] * inv_n;
    float uy  = s[1] * inv_n;
    float uxx = s[2] * inv_n;
    float uyy = s[3] * inv_n;
    float uxy = s[4] * inv_n;
    float vx  = cn * (uxx - ux * ux);
    float vy  = cn * (uyy - uy * uy);
    float vxy = cn * (uxy - ux * uy);
    float num = (2.0f * ux * uy + C1) * (2.0f * vxy + C2);
    float den = (ux * ux + uy * uy + C1) * (vx + vy + C2);
    return __fdividef(num, den);
}

__global__ __launch_bounds__(256) void ssim_slide_kernel(
    const float* __restrict__ pred,
    const float* __restrict__ target,
    double* __restrict__ accum)
{
    __shared__ float hv[2][5][HSTRIDE];   // double-buffered vertical sums
    __shared__ float wsum[4];

    const int band  = blockIdx.x;
    const int plane = blockIdx.y;
    const int t = threadIdx.x;
    const int c = t << 1;                            // columns c, c+1
    const int b = band * BAND_ROWS;                  // first output row
    const int n = (VALID - b < BAND_ROWS) ? (VALID - b) : BAND_ROWS;

    const float* __restrict__ px_ptr = pred   + (size_t)plane * (IMG * IMG) + c;
    const float* __restrict__ py_ptr = target + (size_t)plane * (IMG * IMG) + c;

    // vertical running sums (5 moments x 2 columns)
    float2 Vx  = make_float2(0.f, 0.f);
    float2 Vy  = Vx, Vxx = Vx, Vyy = Vx, Vxy = Vx;
    // raw pixel history, 7 rows (statically indexed everywhere)
    float2 hx[7], hy[7];

    // ---- prologue: input rows b .. b+5 ----
    #pragma unroll
    for (int k = 0; k < 6; ++k) {
        float2 px = *reinterpret_cast<const float2*>(px_ptr + (size_t)(b + k) * IMG);
        float2 py = *reinterpret_cast<const float2*>(py_ptr + (size_t)(b + k) * IMG);
        hx[k] = px; hy[k] = py;
        Vx.x  += px.x;        Vx.y  += px.y;
        Vy.x  += py.x;        Vy.y  += py.y;
        Vxx.x += px.x * px.x; Vxx.y += px.y * px.y;
        Vyy.x += py.x * py.x; Vyy.y += py.y * py.y;
        Vxy.x += px.x * py.x; Vxy.y += px.y * py.y;
    }

    float local = 0.f;

    auto row_step = [&](float2& hxs, float2& hys, bool do_sub, int r, int p) {
        float2 px = *reinterpret_cast<const float2*>(px_ptr + (size_t)r * IMG);
        float2 py = *reinterpret_cast<const float2*>(py_ptr + (size_t)r * IMG);
        if (do_sub) {
            float2 ox = hxs, oy = hys;
            Vx.x  -= ox.x;        Vx.y  -= ox.y;
            Vy.x  -= oy.x;        Vy.y  -= oy.y;
            Vxx.x -= ox.x * ox.x; Vxx.y -= ox.y * ox.y;
            Vyy.x -= oy.x * oy.x; Vyy.y -= oy.y * oy.y;
            Vxy.x -= ox.x * oy.x; Vxy.y -= ox.y * oy.y;
        }
        hxs = px; hys = py;
        Vx.x  += px.x;        Vx.y  += px.y;
        Vy.x  += py.x;        Vy.y  += py.y;
        Vxx.x += px.x * px.x; Vxx.y += px.y * px.y;
        Vyy.x += py.x * py.x; Vyy.y += py.y * py.y;
        Vxy.x += px.x * py.x; Vxy.y += px.y * py.y;

        *reinterpret_cast<float2*>(&hv[p][0][c]) = Vx;
        *reinterpret_cast<float2*>(&hv[p][1][c]) = Vy;
        *reinterpret_cast<float2*>(&hv[p][2][c]) = Vxx;
        *reinterpret_cast<float2*>(&hv[p][3][c]) = Vyy;
        *reinterpret_cast<float2*>(&hv[p][4][c]) = Vxy;
        __syncthreads();

        if (c < VALID) {                 // c even <= 504 -> both cols valid
            float s0[5], s1[5];
            #pragma unroll
            for (int m = 0; m < 5; ++m) {
                const float* row = &hv[p][m][c];
                float2 r0 = *reinterpret_cast<const float2*>(row);
                float2 r1 = *reinterpret_cast<const float2*>(row + 2);
                float2 r2 = *reinterpret_cast<const float2*>(row + 4);
                float2 r3 = *reinterpret_cast<const float2*>(row + 6);
                float a = r0.x + r0.y + r1.x + r1.y + r2.x + r2.y + r3.x;
                s0[m] = a;
                s1[m] = a - r0.x + r3.y;
            }
            local += ssim_val(s0);
            local += ssim_val(s1);
        }
    };

    // step i=0: add input row b+6 (slot 6), no subtract, buffer 0
    row_step(hx[6], hy[6], false, b + 6, 0);

    // steps i=1..n-1, unrolled by 7 so history slot (i-1)%7 == k is static
    for (int ii = 1; ii < BAND_ROWS; ii += 7) {
        #pragma unroll
        for (int k = 0; k < 7; ++k) {
            const int i = ii + k;
            if (i < n)                   // block-uniform (n from blockIdx only)
                row_step(hx[k], hy[k], true, b + 6 + i, i & 1);
        }
    }

    // wave reduce -> cross-wave -> one atomic per block
    #pragma unroll
    for (int off = 32; off > 0; off >>= 1)
        local += __shfl_down(local, off, 64);
    if ((t & 63) == 0) wsum[t >> 6] = local;
    __syncthreads();
    if (t == 0)
        atomicAdd(accum, (double)(wsum[0] + wsum[1] + wsum[2] + wsum[3]));
}

__global__ void ssim_finalize_kernel(const double* __restrict__ accum,
                                     float* __restrict__ out)
{
    const double n_valid = (double)NPLANES * (double)VALID * (double)VALID;
    out[0] = (float)(1.0 - accum[0] / n_valid);
}

extern "C" void kernel_launch(void* const* d_in, const int* in_sizes, int n_in,
                              void* d_out, int out_size, void* d_ws, size_t ws_size,
                              hipStream_t stream) {
    const float* pred   = (const float*)d_in[0];
    const float* target = (const float*)d_in[1];
    float* out = (float*)d_out;
    double* accum = (double*)d_ws;

    hipMemsetAsync(d_ws, 0, sizeof(double), stream);

    dim3 grid(NBANDS, NPLANES);
    ssim_slide_kernel<<<grid, 256, 0, stream>>>(pred, target, accum);
    ssim_finalize_kernel<<<1, 1, 0, stream>>>(accum, out);
}

// Round 3
// 82.525 us; speedup vs baseline: 3.9720x; 1.0698x over previous
//
#include <hip/hip_runtime.h>

#define IMG     512
#define VALID   506          // IMG - 6
#define NPLANES 96           // 32 * 3
#define R       16           // output rows per wave-band
#define BANDS   32           // 32 * 16 = 512 >= 506

__device__ __forceinline__ float shfl_next(float v, int baddr) {
    return __int_as_float(__builtin_amdgcn_ds_bpermute(baddr, __float_as_int(v)));
}

__device__ __forceinline__ void addv(float4& V, const float4 p) {
    V.x += p.x; V.y += p.y; V.z += p.z; V.w += p.w;
}
__device__ __forceinline__ void subv(float4& V, const float4 p) {
    V.x -= p.x; V.y -= p.y; V.z -= p.z; V.w -= p.w;
}
__device__ __forceinline__ void addmul(float4& V, const float4 p, const float4 q) {
    V.x = fmaf(p.x, q.x, V.x); V.y = fmaf(p.y, q.y, V.y);
    V.z = fmaf(p.z, q.z, V.z); V.w = fmaf(p.w, q.w, V.w);
}
__device__ __forceinline__ void submul(float4& V, const float4 p, const float4 q) {
    V.x = fmaf(-p.x, q.x, V.x); V.y = fmaf(-p.y, q.y, V.y);
    V.z = fmaf(-p.z, q.z, V.z); V.w = fmaf(-p.w, q.w, V.w);
}

// horizontal 7-tap sliding sums over this lane's 8 cols + 6 halo cols from lane+1
__device__ __forceinline__ void hsum7(const float4 A, const float4 B, int baddr, float o[8]) {
    float n0 = shfl_next(A.x, baddr);
    float n1 = shfl_next(A.y, baddr);
    float n2 = shfl_next(A.z, baddr);
    float n3 = shfl_next(A.w, baddr);
    float n4 = shfl_next(B.x, baddr);
    float n5 = shfl_next(B.y, baddr);
    o[0] = ((A.x + A.y) + (A.z + A.w)) + ((B.x + B.y) + B.z);
    o[1] = (o[0] - A.x) + B.w;
    o[2] = (o[1] - A.y) + n0;
    o[3] = (o[2] - A.z) + n1;
    o[4] = (o[3] - A.w) + n2;
    o[5] = (o[4] - B.x) + n3;
    o[6] = (o[5] - B.y) + n4;
    o[7] = (o[6] - B.z) + n5;
}

#define LOADROW(x0, x1, y0, y1, r) do {                                         \
    const float4* _p = reinterpret_cast<const float4*>(pp + (size_t)(r) * IMG); \
    const float4* _q = reinterpret_cast<const float4*>(pt + (size_t)(r) * IMG); \
    x0 = _p[0]; x1 = _p[1]; y0 = _q[0]; y1 = _q[1]; } while (0)

__global__ __launch_bounds__(256, 3) void ssim_wave_kernel(
    const float* __restrict__ pred,
    const float* __restrict__ target,
    double* __restrict__ accum)
{
    __shared__ float wsum[4];

    const int t     = threadIdx.x;
    const int lane  = t & 63;
    const int wv    = t >> 6;
    const int band  = blockIdx.x * 4 + wv;     // adjacent bands share halo rows in L1/L2
    const int plane = blockIdx.y;
    const int row0  = band * R;
    const int col   = lane << 3;               // this lane's 8 columns

    const size_t pbase = (size_t)plane * (IMG * IMG);
    const float* __restrict__ pp = pred   + pbase + col;
    const float* __restrict__ pt = target + pbase + col;

    const int baddr = ((lane + 1) & 63) << 2;  // ds_bpermute addr: lane+1

    float4 z = make_float4(0.f, 0.f, 0.f, 0.f);
    float4 Vx_a = z, Vx_b = z, Vy_a = z, Vy_b = z;
    float4 Vxx_a = z, Vxx_b = z, Vyy_a = z, Vyy_b = z, Vxy_a = z, Vxy_b = z;

    float4 nx0, nx1, ny0, ny1;                 // prefetched next row
    LOADROW(nx0, nx1, ny0, ny1, row0);

    // ---- prologue: accumulate input rows row0 .. row0+5 ----
    #pragma unroll 2
    for (int k = 0; k < 6; ++k) {
        float4 px0 = nx0, px1 = nx1, py0 = ny0, py1 = ny1;
        LOADROW(nx0, nx1, ny0, ny1, row0 + k + 1);   // k=5 -> row0+6 (first main row)
        addv(Vx_a, px0);  addv(Vx_b, px1);
        addv(Vy_a, py0);  addv(Vy_b, py1);
        addmul(Vxx_a, px0, px0); addmul(Vxx_b, px1, px1);
        addmul(Vyy_a, py0, py0); addmul(Vyy_b, py1, py1);
        addmul(Vxy_a, px0, py0); addmul(Vxy_b, px1, py1);
    }

    const float c1 = 0.9604f;   // (0.01*2)^2 * 49^2
    const float c2 = 8.4672f;   // (0.03*2)^2 * 48*49
    float local = 0.f;

    #pragma unroll 2
    for (int i = 0; i < R; ++i) {
        float4 px0 = nx0, px1 = nx1, py0 = ny0, py1 = ny1;

        // old row leaving the window: re-load (guaranteed L1/L2-hot, loaded 7 rows ago)
        float4 ox0, ox1, oy0, oy1;
        const bool has_old = (i > 0);
        if (has_old) LOADROW(ox0, ox1, oy0, oy1, row0 + i - 1);

        // prefetch next new row (clamped; last-iter prefetch is harmless)
        int rn = row0 + 7 + i; rn = rn < IMG - 1 ? rn : IMG - 1;
        LOADROW(nx0, nx1, ny0, ny1, rn);

        // vertical sliding update
        addv(Vx_a, px0);  addv(Vx_b, px1);
        addv(Vy_a, py0);  addv(Vy_b, py1);
        addmul(Vxx_a, px0, px0); addmul(Vxx_b, px1, px1);
        addmul(Vyy_a, py0, py0); addmul(Vyy_b, py1, py1);
        addmul(Vxy_a, px0, py0); addmul(Vxy_b, px1, py1);
        if (has_old) {
            subv(Vx_a, ox0);  subv(Vx_b, ox1);
            subv(Vy_a, oy0);  subv(Vy_b, oy1);
            submul(Vxx_a, ox0, ox0); submul(Vxx_b, ox1, ox1);
            submul(Vyy_a, oy0, oy0); submul(Vyy_b, oy1, oy1);
            submul(Vxy_a, ox0, oy0); submul(Vxy_b, ox1, oy1);
        }

        const bool row_ok = (row0 + i) < VALID;   // wave-uniform
        if (row_ok) {
            float hx[8], hy[8], hxx[8], hyy[8], hxy[8];
            hsum7(Vx_a,  Vx_b,  baddr, hx);
            hsum7(Vy_a,  Vy_b,  baddr, hy);
            hsum7(Vxx_a, Vxx_b, baddr, hxx);
            hsum7(Vyy_a, Vyy_b, baddr, hyy);
            hsum7(Vxy_a, Vxy_b, baddr, hxy);
            #pragma unroll
            for (int j = 0; j < 8; ++j) {
                float t1 = hx[j] * hy[j];
                float t2 = fmaf(hx[j], hx[j], hy[j] * hy[j]);
                float n1 = fmaf(2.f, t1, c1);
                float d1 = t2 + c1;
                float n2 = fmaf(-2.f, t1, fmaf(98.f, hxy[j], c2));
                float d2 = fmaf(49.f, hxx[j] + hyy[j], c2) - t2;
                float S  = __fdividef(n1 * n2, d1 * d2);
                local += (col + j < VALID) ? S : 0.f;
            }
        }
    }

    // wave reduce -> cross-wave -> one atomic per block
    #pragma unroll
    for (int off = 32; off > 0; off >>= 1)
        local += __shfl_down(local, off, 64);
    if (lane == 0) wsum[wv] = local;
    __syncthreads();
    if (t == 0)
        atomicAdd(accum, (double)(wsum[0] + wsum[1] + wsum[2] + wsum[3]));
}

__global__ void ssim_finalize_kernel(const double* __restrict__ accum,
                                     float* __restrict__ out)
{
    const double n_valid = (double)NPLANES * (double)VALID * (double)VALID;
    out[0] = (float)(1.0 - accum[0] / n_valid);
}

extern "C" void kernel_launch(void* const* d_in, const int* in_sizes, int n_in,
                              void* d_out, int out_size, void* d_ws, size_t ws_size,
                              hipStream_t stream) {
    const float* pred   = (const float*)d_in[0];
    const float* target = (const float*)d_in[1];
    float* out = (float*)d_out;
    double* accum = (double*)d_ws;

    hipMemsetAsync(d_ws, 0, sizeof(double), stream);

    dim3 grid(BANDS / 4, NPLANES);   // 8 x 96 = 768 blocks, 4 wave-bands each
    ssim_wave_kernel<<<grid, 256, 0, stream>>>(pred, target, accum);
    ssim_finalize_kernel<<<1, 1, 0, stream>>>(accum, out);
}

// Round 4
// 72.478 us; speedup vs baseline: 4.5226x; 1.1386x over previous
//
#include <hip/hip_runtime.h>

#define IMG     512
#define VALID   506          // IMG - 6
#define NPLANES 96           // 32 * 3
#define R       8            // output rows per wave-band
#define NBANDS  64           // 64 * 8 = 512 >= 506

__device__ __forceinline__ float shfl_next(float v, int baddr) {
    return __int_as_float(__builtin_amdgcn_ds_bpermute(baddr, __float_as_int(v)));
}

__device__ __forceinline__ void addv(float4& V, const float4 p) {
    V.x += p.x; V.y += p.y; V.z += p.z; V.w += p.w;
}
__device__ __forceinline__ void subv(float4& V, const float4 p) {
    V.x -= p.x; V.y -= p.y; V.z -= p.z; V.w -= p.w;
}
__device__ __forceinline__ void addmul(float4& V, const float4 p, const float4 q) {
    V.x = fmaf(p.x, q.x, V.x); V.y = fmaf(p.y, q.y, V.y);
    V.z = fmaf(p.z, q.z, V.z); V.w = fmaf(p.w, q.w, V.w);
}
__device__ __forceinline__ void submul(float4& V, const float4 p, const float4 q) {
    V.x = fmaf(-p.x, q.x, V.x); V.y = fmaf(-p.y, q.y, V.y);
    V.z = fmaf(-p.z, q.z, V.z); V.w = fmaf(-p.w, q.w, V.w);
}

// horizontal 7-tap sliding sums over this lane's 8 cols + 6 halo cols from lane+1
__device__ __forceinline__ void hsum7(const float4 A, const float4 B, int baddr, float o[8]) {
    float n0 = shfl_next(A.x, baddr);
    float n1 = shfl_next(A.y, baddr);
    float n2 = shfl_next(A.z, baddr);
    float n3 = shfl_next(A.w, baddr);
    float n4 = shfl_next(B.x, baddr);
    float n5 = shfl_next(B.y, baddr);
    o[0] = ((A.x + A.y) + (A.z + A.w)) + ((B.x + B.y) + B.z);
    o[1] = (o[0] - A.x) + B.w;
    o[2] = (o[1] - A.y) + n0;
    o[3] = (o[2] - A.z) + n1;
    o[4] = (o[3] - A.w) + n2;
    o[5] = (o[4] - B.x) + n3;
    o[6] = (o[5] - B.y) + n4;
    o[7] = (o[6] - B.z) + n5;
}

#define LOADROW(x0, x1, y0, y1, r) do {                                         \
    const float4* _p = reinterpret_cast<const float4*>(pp + (size_t)(r) * IMG); \
    const float4* _q = reinterpret_cast<const float4*>(pt + (size_t)(r) * IMG); \
    x0 = _p[0]; x1 = _p[1]; y0 = _q[0]; y1 = _q[1]; } while (0)

__global__ __launch_bounds__(256) void ssim_wave_kernel(
    const float* __restrict__ pred,
    const float* __restrict__ target,
    double* __restrict__ accum)
{
    __shared__ float wsum[4];

    const int t     = threadIdx.x;
    const int lane  = t & 63;
    const int wv    = t >> 6;
    const int band  = blockIdx.x * 4 + wv;     // adjacent bands in one block share halos
    const int plane = blockIdx.y;
    const int row0  = band * R;
    const int col   = lane << 3;                // this lane's 8 columns

    const size_t pbase = (size_t)plane * (IMG * IMG);
    const float* __restrict__ pp = pred   + pbase + col;
    const float* __restrict__ pt = target + pbase + col;

    const int baddr = ((lane + 1) & 63) << 2;   // ds_bpermute addr: lane+1

    float4 z = make_float4(0.f, 0.f, 0.f, 0.f);
    float4 Vx_a = z, Vx_b = z, Vy_a = z, Vy_b = z;
    float4 Vss_a = z, Vss_b = z, Vxy_a = z, Vxy_b = z;   // Vss = Vxx + Vyy merged

    float4 nx0, nx1, ny0, ny1;                  // prefetched incoming row
    LOADROW(nx0, nx1, ny0, ny1, row0);

    // ---- prologue: accumulate input rows row0 .. row0+5 ----
    #pragma unroll
    for (int k = 0; k < 6; ++k) {
        float4 px0 = nx0, px1 = nx1, py0 = ny0, py1 = ny1;
        LOADROW(nx0, nx1, ny0, ny1, row0 + k + 1);    // k=5 -> row0+6 (iter-0 row)
        addv(Vx_a, px0);  addv(Vx_b, px1);
        addv(Vy_a, py0);  addv(Vy_b, py1);
        addmul(Vss_a, px0, px0); addmul(Vss_b, px1, px1);
        addmul(Vss_a, py0, py0); addmul(Vss_b, py1, py1);
        addmul(Vxy_a, px0, py0); addmul(Vxy_b, px1, py1);
    }

    // old-row prefetch for iter 1 (iter 0 has no subtract)
    float4 pox0, pox1, poy0, poy1;
    LOADROW(pox0, pox1, poy0, poy1, row0);

    const float c1 = 0.9604f;   // (0.01*2)^2 * 49^2
    const float c2 = 8.4672f;   // (0.03*2)^2 * 48*49
    float local = 0.f;

    #pragma unroll
    for (int i = 0; i < R; ++i) {
        float4 px0 = nx0, px1 = nx1, py0 = ny0, py1 = ny1;
        float4 ox0 = pox0, ox1 = pox1, oy0 = poy0, oy1 = poy1;

        // prefetch for iter i+1: incoming row row0+7+i (clamped), old row row0+i
        if (i < R - 1) {
            int rn = row0 + 7 + i; rn = rn < IMG - 1 ? rn : IMG - 1;
            LOADROW(nx0, nx1, ny0, ny1, rn);
            if (i > 0) LOADROW(pox0, pox1, poy0, poy1, row0 + i);
        }

        // vertical sliding update
        addv(Vx_a, px0);  addv(Vx_b, px1);
        addv(Vy_a, py0);  addv(Vy_b, py1);
        addmul(Vss_a, px0, px0); addmul(Vss_b, px1, px1);
        addmul(Vss_a, py0, py0); addmul(Vss_b, py1, py1);
        addmul(Vxy_a, px0, py0); addmul(Vxy_b, px1, py1);
        if (i > 0) {
            subv(Vx_a, ox0);  subv(Vx_b, ox1);
            subv(Vy_a, oy0);  subv(Vy_b, oy1);
            submul(Vss_a, ox0, ox0); submul(Vss_b, ox1, ox1);
            submul(Vss_a, oy0, oy0); submul(Vss_b, oy1, oy1);
            submul(Vxy_a, ox0, oy0); submul(Vxy_b, ox1, oy1);
        }

        const bool row_ok = (row0 + i) < VALID;   // wave-uniform
        if (row_ok) {
            float hx[8], hy[8], hss[8], hxy[8];
            hsum7(Vx_a,  Vx_b,  baddr, hx);
            hsum7(Vy_a,  Vy_b,  baddr, hy);
            hsum7(Vss_a, Vss_b, baddr, hss);
            hsum7(Vxy_a, Vxy_b, baddr, hxy);
            #pragma unroll
            for (int j = 0; j < 8; ++j) {
                float t1 = hx[j] * hy[j];
                float t2 = fmaf(hx[j], hx[j], hy[j] * hy[j]);
                float n1 = fmaf(2.f, t1, c1);
                float d1 = t2 + c1;
                float n2 = fmaf(-2.f, t1, fmaf(98.f, hxy[j], c2));
                float d2 = fmaf(49.f, hss[j], c2) - t2;
                float S  = __fdividef(n1 * n2, d1 * d2);
                local += (col + j < VALID) ? S : 0.f;
            }
        }
    }

    // wave reduce -> cross-wave -> one atomic per block
    #pragma unroll
    for (int off = 32; off > 0; off >>= 1)
        local += __shfl_down(local, off, 64);
    if (lane == 0) wsum[wv] = local;
    __syncthreads();
    if (t == 0)
        atomicAdd(accum, (double)(wsum[0] + wsum[1] + wsum[2] + wsum[3]));
}

__global__ void ssim_finalize_kernel(const double* __restrict__ accum,
                                     float* __restrict__ out)
{
    const double n_valid = (double)NPLANES * (double)VALID * (double)VALID;
    out[0] = (float)(1.0 - accum[0] / n_valid);
}

extern "C" void kernel_launch(void* const* d_in, const int* in_sizes, int n_in,
                              void* d_out, int out_size, void* d_ws, size_t ws_size,
                              hipStream_t stream) {
    const float* pred   = (const float*)d_in[0];
    const float* target = (const float*)d_in[1];
    float* out = (float*)d_out;
    double* accum = (double*)d_ws;

    hipMemsetAsync(d_ws, 0, sizeof(double), stream);

    dim3 grid(NBANDS / 4, NPLANES);   // 16 x 96 = 1536 blocks, 4 wave-bands each
    ssim_wave_kernel<<<grid, 256, 0, stream>>>(pred, target, accum);
    ssim_finalize_kernel<<<1, 1, 0, stream>>>(accum, out);
}